// Round 3
// baseline (444.689 us; speedup 1.0000x reference)
//
#include <hip/hip_runtime.h>
#include <hip/hip_bf16.h>

// Causal self-attention, B=8 T=1024 C=1024 H=16 D=64, fp32 in/out.
// Pipeline: cast->bf16 | QKV gemm (MFMA, V stored transposed) |
//           flash attn (MFMA, barrier-free, LDS-free) | proj gemm (MFMA).
// ws layout (bytes): [0,16M) x_bf16 (reused as y_bf16), [16M,24M) weights bf16,
// [24M,72M) K [B,H,T,D] / Q [B,H,T,D] / V^T [B,H,D,T]. Requires ws >= 72MB.

typedef __attribute__((ext_vector_type(8))) short short8;
typedef __attribute__((ext_vector_type(8))) unsigned short ushort8;
typedef __attribute__((ext_vector_type(4))) unsigned short ushort4_t;
typedef __attribute__((ext_vector_type(4))) unsigned int uintx4;
typedef __attribute__((ext_vector_type(4))) float floatx4;

#define LOG2E 1.44269504088896f

__device__ __forceinline__ unsigned short f2bf(float f) {
  unsigned int u = __float_as_uint(f);
  u += 0x7FFFu + ((u >> 16) & 1u);   // RNE
  return (unsigned short)(u >> 16);
}

__device__ __forceinline__ unsigned int pack2bf(float lo, float hi) {
  return (unsigned int)f2bf(lo) | ((unsigned int)f2bf(hi) << 16);
}

__device__ __forceinline__ void gload_lds16(const void* g, void* l) {
  __builtin_amdgcn_global_load_lds(
      (const __attribute__((address_space(1))) unsigned int*)g,
      (__attribute__((address_space(3))) unsigned int*)l, 16, 0, 0);
}

// ---------------- cast fp32 -> bf16, 8 elems/thread ----------------
__global__ __launch_bounds__(256) void cast_bf16_kernel(
    const float* __restrict__ in, unsigned short* __restrict__ out, int n8) {
  int idx = blockIdx.x * 256 + threadIdx.x;
  int stride = gridDim.x * 256;
  for (int i = idx; i < n8; i += stride) {
    const float4* p = reinterpret_cast<const float4*>(in + (size_t)i * 8);
    float4 a = p[0], b = p[1];
    ushort8 r;
    r[0] = f2bf(a.x); r[1] = f2bf(a.y); r[2] = f2bf(a.z); r[3] = f2bf(a.w);
    r[4] = f2bf(b.x); r[5] = f2bf(b.y); r[6] = f2bf(b.z); r[7] = f2bf(b.w);
    *reinterpret_cast<ushort8*>(out + (size_t)i * 8) = r;
  }
}

// ---------------- bf16 GEMM: C[m,n] = sum_k A[m,k]*B[n,k] ----------------
// MODE 0: A=x_bf16[8192x1024], B=weight z (Wk/Wq/Wv). z=0,1 -> bf16 [B,H,T,D];
//         z=2 (V) -> bf16 TRANSPOSED [B,H,D,T].
// MODE 1: A=y_bf16 [8192x1024], B=Wp, out -> fp32 [8192x1024] + bias
template <int MODE>
__global__ __launch_bounds__(256) void gemm_kernel(
    const unsigned short* __restrict__ A, const unsigned short* __restrict__ Bbase,
    unsigned short* __restrict__ outb, float* __restrict__ outf,
    const float* __restrict__ bias) {
  const int tid = threadIdx.x;
  const int lane = tid & 63;
  const int w = tid >> 6;
  const int wr = w >> 1, wc = w & 1;
  const int g = lane >> 4, r = lane & 15;
  const int m0 = blockIdx.y * 128;
  const int n0 = blockIdx.x * 128;

  const unsigned short* Bw =
      (MODE == 0) ? (Bbase + (size_t)blockIdx.z * 1048576) : Bbase;

  __shared__ unsigned short sA[128 * 32];
  __shared__ unsigned short sB[128 * 32];

  floatx4 acc[4][4];
#pragma unroll
  for (int i = 0; i < 4; ++i)
#pragma unroll
    for (int j = 0; j < 4; ++j) acc[i][j] = (floatx4)0.0f;

  for (int kt = 0; kt < 32; ++kt) {
    __syncthreads();  // previous iteration's frag reads complete
#pragma unroll
    for (int c = 0; c < 2; ++c) {
      int ci = tid + c * 256;       // 16B chunk id 0..511
      int row = ci >> 2;            // 0..127
      int colb = (ci & 3) * 16;     // byte within 64B (=BK) row
      const char* gA = (const char*)A + (size_t)(m0 + row) * 2048 + (size_t)kt * 64 + colb;
      gload_lds16(gA, &sA[(w * 64 + c * 256) * 8]);
      const char* gB = (const char*)Bw + (size_t)(n0 + row) * 2048 + (size_t)kt * 64 + colb;
      gload_lds16(gB, &sB[(w * 64 + c * 256) * 8]);
    }
    __syncthreads();  // staging done

    short8 aF[4], bF[4];
#pragma unroll
    for (int mf = 0; mf < 4; ++mf)
      aF[mf] = *reinterpret_cast<const short8*>(&sA[(wr * 64 + mf * 16 + r) * 32 + g * 8]);
#pragma unroll
    for (int nf = 0; nf < 4; ++nf)
      bF[nf] = *reinterpret_cast<const short8*>(&sB[(wc * 64 + nf * 16 + r) * 32 + g * 8]);
#pragma unroll
    for (int mf = 0; mf < 4; ++mf)
#pragma unroll
      for (int nf = 0; nf < 4; ++nf)
        acc[mf][nf] = __builtin_amdgcn_mfma_f32_16x16x32_bf16(aF[mf], bF[nf], acc[mf][nf], 0, 0, 0);
  }

  if (MODE == 0) {
    unsigned short* outz = outb + (size_t)blockIdx.z * 8388608;
    if (blockIdx.z == 2) {
      // V^T: [b,h,d,t]; acc[mf][nf][q] = V[m = b*1024+t][n = h*64+d]
#pragma unroll
      for (int mf = 0; mf < 4; ++mf)
#pragma unroll
        for (int nf = 0; nf < 4; ++nf) {
          int m = m0 + wr * 64 + mf * 16 + g * 4;  // 4 consecutive t (q=0..3)
          int n = n0 + wc * 64 + nf * 16 + r;
          int b = m >> 10, t = m & 1023, h = n >> 6, d = n & 63;
          ushort4_t pk;
          pk[0] = f2bf(acc[mf][nf][0]); pk[1] = f2bf(acc[mf][nf][1]);
          pk[2] = f2bf(acc[mf][nf][2]); pk[3] = f2bf(acc[mf][nf][3]);
          *reinterpret_cast<ushort4_t*>(
              &outz[((size_t)((b * 16 + h) * 64 + d)) * 1024 + t]) = pk;
        }
    } else {
#pragma unroll
      for (int mf = 0; mf < 4; ++mf)
#pragma unroll
        for (int nf = 0; nf < 4; ++nf)
#pragma unroll
          for (int q = 0; q < 4; ++q) {
            int m = m0 + wr * 64 + mf * 16 + g * 4 + q;   // row = b*1024+t
            int n = n0 + wc * 64 + nf * 16 + r;           // col = h*64+d
            int b = m >> 10, t = m & 1023, h = n >> 6, d = n & 63;
            outz[(size_t)((b * 16 + h) * 1024 + t) * 64 + d] = f2bf(acc[mf][nf][q]);
          }
    }
  } else {
#pragma unroll
    for (int mf = 0; mf < 4; ++mf)
#pragma unroll
      for (int nf = 0; nf < 4; ++nf) {
        int n = n0 + wc * 64 + nf * 16 + r;
        float bv = bias[n];
#pragma unroll
        for (int q = 0; q < 4; ++q) {
          int m = m0 + wr * 64 + mf * 16 + g * 4 + q;
          outf[(size_t)m * 1024 + n] = acc[mf][nf][q] + bv;
        }
      }
  }
}

// ---------------- flash attention (barrier-free, LDS-free) ----------------
// Reference: att = (K @ Q^T)*D^-0.5, tril mask (keep j<=i), softmax over j,
// Y = att @ V.  We compute S^T = Q.K^T so softmax axis j is the MFMA row dim
// and each lane owns a single i-column (i = iw + (lane&15)), then
// Y^T = V^T . P^T, keeping lane layout col=i throughout.  No LDS, no barriers.
__global__ __launch_bounds__(256) void attn_kernel(
    const unsigned short* __restrict__ kqv, unsigned short* __restrict__ y) {
  const int tid = threadIdx.x;
  const int lane = tid & 63;
  const int w = tid >> 6;
  const int g = lane >> 4, r = lane & 15;
  const int bh = blockIdx.y;
  const int it = blockIdx.x;
  const int i0 = it * 64;
  const int iw = i0 + w * 16;        // this wave's 16 i-rows; lane's i = iw + r

  const unsigned short* Kh = kqv + (size_t)bh * 65536;
  const unsigned short* Qh = kqv + 8388608u + (size_t)bh * 65536;
  const unsigned short* Vt = kqv + 16777216u + (size_t)bh * 65536;  // [d][t]

  // bK[s]: B-frag (col=i, k=d): lane holds K[iw + r][s*32 + g*8 + e]
  short8 bK[2];
#pragma unroll
  for (int s = 0; s < 2; ++s)
    bK[s] = *reinterpret_cast<const short8*>(&Kh[(size_t)(iw + r) * 64 + s * 32 + g * 8]);

  floatx4 accYT[4];  // [df]: lane holds Y^T[d = df*16 + g*4 + q][i = iw + r]
#pragma unroll
  for (int df = 0; df < 4; ++df) accYT[df] = (floatx4)0.0f;
  float m_run = -1e30f, l_run = 0.0f;

  for (int jt = 0; jt <= it; ++jt) {
    const int j0 = jt * 64;
    // ---- S^T = Q.K^T : sT[jf] lane holds S^T[j = j0+jf*16+g*4+q][i = iw+r]
    short8 aQ[4][2];
#pragma unroll
    for (int jf = 0; jf < 4; ++jf)
#pragma unroll
      for (int s = 0; s < 2; ++s)
        aQ[jf][s] = *reinterpret_cast<const short8*>(
            &Qh[(size_t)(j0 + jf * 16 + r) * 64 + s * 32 + g * 8]);
    // prefetch V frags for PV (hide L2 latency under softmax VALU)
    short8 aV[4][2];
#pragma unroll
    for (int df = 0; df < 4; ++df)
#pragma unroll
      for (int s = 0; s < 2; ++s)
        aV[df][s] = *reinterpret_cast<const short8*>(
            &Vt[(size_t)(df * 16 + r) * 1024 + j0 + s * 32 + g * 8]);

    floatx4 sT[4];
    __builtin_amdgcn_s_setprio(1);
#pragma unroll
    for (int jf = 0; jf < 4; ++jf) {
      sT[jf] = (floatx4)0.0f;
#pragma unroll
      for (int s = 0; s < 2; ++s)
        sT[jf] = __builtin_amdgcn_mfma_f32_16x16x32_bf16(aQ[jf][s], bK[s], sT[jf], 0, 0, 0);
    }
    __builtin_amdgcn_s_setprio(0);

    // ---- scale + causal mask (j > i -> -inf), diagonal tile only
    const bool diag = (jt == it);
    const int i_lane = iw + r;
#pragma unroll
    for (int jf = 0; jf < 4; ++jf)
#pragma unroll
      for (int q = 0; q < 4; ++q) {
        float v = sT[jf][q] * 0.125f;
        if (diag && (j0 + jf * 16 + g * 4 + q > i_lane)) v = -1e30f;
        sT[jf][q] = v;
      }

    // ---- online softmax over j for this lane's column i (reduce across g)
    float mx = sT[0][0];
#pragma unroll
    for (int jf = 0; jf < 4; ++jf)
#pragma unroll
      for (int q = 0; q < 4; ++q) mx = fmaxf(mx, sT[jf][q]);
    mx = fmaxf(mx, __shfl_xor(mx, 16));
    mx = fmaxf(mx, __shfl_xor(mx, 32));
    float mnew = fmaxf(m_run, mx);
    float corr = exp2f((m_run - mnew) * LOG2E);
    m_run = mnew;

    float ssum = 0.0f;
#pragma unroll
    for (int jf = 0; jf < 4; ++jf)
#pragma unroll
      for (int q = 0; q < 4; ++q) {
        float p = exp2f((sT[jf][q] - mnew) * LOG2E);
        sT[jf][q] = p;
        ssum += p;
      }
    ssum += __shfl_xor(ssum, 16);
    ssum += __shfl_xor(ssum, 32);
    l_run = l_run * corr + ssum;
#pragma unroll
    for (int df = 0; df < 4; ++df) accYT[df] *= corr;

    // ---- P^T (C-layout) -> B-frag for PV via packed bf16 + shuffles
    // source word pk[jf][h] at lane (gs,r) = P^T[j = jf*16+gs*4+2h+{0,1}][i=r..]
    unsigned int pk[4][2];
#pragma unroll
    for (int jf = 0; jf < 4; ++jf) {
      pk[jf][0] = pack2bf(sT[jf][0], sT[jf][1]);
      pk[jf][1] = pack2bf(sT[jf][2], sT[jf][3]);
    }
    short8 bP[2];
#pragma unroll
    for (int s = 0; s < 2; ++s) {
      uintx4 wd;
#pragma unroll
      for (int w_ = 0; w_ < 4; ++w_) {
        int src = (((g & 1) * 2 + (w_ >> 1)) << 4) + r;
        unsigned int t0 = (unsigned int)__shfl((int)pk[2 * s][w_ & 1], src);
        unsigned int t1 = (unsigned int)__shfl((int)pk[2 * s + 1][w_ & 1], src);
        wd[w_] = (g & 2) ? t1 : t0;
      }
      bP[s] = __builtin_bit_cast(short8, wd);
    }

    // ---- Y^T += V^T . P^T
    __builtin_amdgcn_s_setprio(1);
#pragma unroll
    for (int df = 0; df < 4; ++df)
#pragma unroll
      for (int s = 0; s < 2; ++s)
        accYT[df] = __builtin_amdgcn_mfma_f32_16x16x32_bf16(aV[df][s], bP[s], accYT[df], 0, 0, 0);
    __builtin_amdgcn_s_setprio(0);
  }

  // ---- epilogue: y[b, t=i, h*64+d] = Y^T[d][i] / l ; lane i = iw + r
  const float inv = 1.0f / l_run;
  const int b = bh >> 4, h = bh & 15;
  const int t = iw + r;
  unsigned short* row = y + (size_t)(b * 1024 + t) * 1024 + h * 64;
#pragma unroll
  for (int df = 0; df < 4; ++df) {
    ushort4_t pkv;
    pkv[0] = f2bf(accYT[df][0] * inv);
    pkv[1] = f2bf(accYT[df][1] * inv);
    pkv[2] = f2bf(accYT[df][2] * inv);
    pkv[3] = f2bf(accYT[df][3] * inv);
    *reinterpret_cast<ushort4_t*>(&row[df * 16 + g * 4]) = pkv;
  }
}

extern "C" void kernel_launch(void* const* d_in, const int* in_sizes, int n_in,
                              void* d_out, int out_size, void* d_ws, size_t ws_size,
                              hipStream_t stream) {
  const float* x  = (const float*)d_in[0];
  const float* Wk = (const float*)d_in[1];
  const float* Wq = (const float*)d_in[2];
  const float* Wv = (const float*)d_in[3];
  const float* Wp = (const float*)d_in[4];
  const float* bp = (const float*)d_in[5];
  float* out = (float*)d_out;

  char* ws = (char*)d_ws;
  unsigned short* xb  = (unsigned short*)ws;                  // 8M elems (reused as y)
  unsigned short* wb  = (unsigned short*)(ws + (16u << 20));  // 4 x 1M elems
  unsigned short* kqv = (unsigned short*)(ws + (24u << 20));  // K,Q [B,H,T,D]; V^T [B,H,D,T]

  cast_bf16_kernel<<<2048, 256, 0, stream>>>(x, xb, 1048576);
  cast_bf16_kernel<<<512, 256, 0, stream>>>(Wk, wb + 0 * 1048576, 131072);
  cast_bf16_kernel<<<512, 256, 0, stream>>>(Wq, wb + 1 * 1048576, 131072);
  cast_bf16_kernel<<<512, 256, 0, stream>>>(Wv, wb + 2 * 1048576, 131072);
  cast_bf16_kernel<<<512, 256, 0, stream>>>(Wp, wb + 3 * 1048576, 131072);

  dim3 gqkv(8, 64, 3);  // (N/128, M/128, 3 weights)
  gemm_kernel<0><<<gqkv, 256, 0, stream>>>(xb, wb, kqv, nullptr, nullptr);

  attn_kernel<<<dim3(16, 128), 256, 0, stream>>>(kqv, xb /* y_bf16 */);

  gemm_kernel<1><<<dim3(8, 64, 1), 256, 0, stream>>>(xb, wb + 3 * 1048576, nullptr, out, bp);
}

// Round 6
// 277.665 us; speedup vs baseline: 1.6015x; 1.6015x over previous
//
#include <hip/hip_runtime.h>
#include <hip/hip_bf16.h>

// Causal self-attention, B=8 T=1024 C=1024 H=16 D=64, fp32 in/out.
// Pipeline: cast->bf16 | QKV gemm (MFMA, V stored transposed) |
//           flash attn (MFMA, LDS double-buffered Q/V^T, swapped QK^T,
//           in-register softmax, balanced causal tile pairs) | proj gemm.
// ws: [0,16M) x_bf16 (reused as y_bf16), [16M,24M) weights bf16,
// [24M,72M) K [B,H,T,D] / Q [B,H,T,D] / V^T [B,H,D,T]. Requires ws >= 72MB.

typedef __attribute__((ext_vector_type(8))) short short8;
typedef __attribute__((ext_vector_type(8))) unsigned short ushort8;
typedef __attribute__((ext_vector_type(4))) unsigned short ushort4_t;
typedef __attribute__((ext_vector_type(4))) unsigned int uintx4;
typedef __attribute__((ext_vector_type(4))) float floatx4;

#define LOG2E 1.44269504088896f

__device__ __forceinline__ unsigned short f2bf(float f) {
  unsigned int u = __float_as_uint(f);
  u += 0x7FFFu + ((u >> 16) & 1u);   // RNE
  return (unsigned short)(u >> 16);
}

__device__ __forceinline__ unsigned int pack2bf(float lo, float hi) {
  return (unsigned int)f2bf(lo) | ((unsigned int)f2bf(hi) << 16);
}

__device__ __forceinline__ void gload_lds16(const void* g, void* l) {
  __builtin_amdgcn_global_load_lds(
      (const __attribute__((address_space(1))) unsigned int*)g,
      (__attribute__((address_space(3))) unsigned int*)l, 16, 0, 0);
}

// ---------------- cast fp32 -> bf16, 8 elems/thread ----------------
__global__ __launch_bounds__(256) void cast_bf16_kernel(
    const float* __restrict__ in, unsigned short* __restrict__ out, int n8) {
  int idx = blockIdx.x * 256 + threadIdx.x;
  int stride = gridDim.x * 256;
  for (int i = idx; i < n8; i += stride) {
    const float4* p = reinterpret_cast<const float4*>(in + (size_t)i * 8);
    float4 a = p[0], b = p[1];
    ushort8 r;
    r[0] = f2bf(a.x); r[1] = f2bf(a.y); r[2] = f2bf(a.z); r[3] = f2bf(a.w);
    r[4] = f2bf(b.x); r[5] = f2bf(b.y); r[6] = f2bf(b.z); r[7] = f2bf(b.w);
    *reinterpret_cast<ushort8*>(out + (size_t)i * 8) = r;
  }
}

// ---------------- bf16 GEMM: C[m,n] = sum_k A[m,k]*B[n,k] ----------------
// MODE 0: A=x_bf16[8192x1024], B=weight z (Wk/Wq/Wv). z=0,1 -> bf16 [B,H,T,D];
//         z=2 (V) -> bf16 TRANSPOSED [B,H,D,T].
// MODE 1: A=y_bf16 [8192x1024], B=Wp, out -> fp32 [8192x1024] + bias
template <int MODE>
__global__ __launch_bounds__(256) void gemm_kernel(
    const unsigned short* __restrict__ A, const unsigned short* __restrict__ Bbase,
    unsigned short* __restrict__ outb, float* __restrict__ outf,
    const float* __restrict__ bias) {
  const int tid = threadIdx.x;
  const int lane = tid & 63;
  const int w = tid >> 6;
  const int wr = w >> 1, wc = w & 1;
  const int g = lane >> 4, r = lane & 15;
  const int m0 = blockIdx.y * 128;
  const int n0 = blockIdx.x * 128;

  const unsigned short* Bw =
      (MODE == 0) ? (Bbase + (size_t)blockIdx.z * 1048576) : Bbase;

  __shared__ unsigned short sA[128 * 32];
  __shared__ unsigned short sB[128 * 32];

  floatx4 acc[4][4];
#pragma unroll
  for (int i = 0; i < 4; ++i)
#pragma unroll
    for (int j = 0; j < 4; ++j) acc[i][j] = (floatx4)0.0f;

  for (int kt = 0; kt < 32; ++kt) {
    __syncthreads();
#pragma unroll
    for (int c = 0; c < 2; ++c) {
      int ci = tid + c * 256;
      int row = ci >> 2;
      int colb = (ci & 3) * 16;
      const char* gA = (const char*)A + (size_t)(m0 + row) * 2048 + (size_t)kt * 64 + colb;
      gload_lds16(gA, &sA[(w * 64 + c * 256) * 8]);
      const char* gB = (const char*)Bw + (size_t)(n0 + row) * 2048 + (size_t)kt * 64 + colb;
      gload_lds16(gB, &sB[(w * 64 + c * 256) * 8]);
    }
    __syncthreads();

    short8 aF[4], bF[4];
#pragma unroll
    for (int mf = 0; mf < 4; ++mf)
      aF[mf] = *reinterpret_cast<const short8*>(&sA[(wr * 64 + mf * 16 + r) * 32 + g * 8]);
#pragma unroll
    for (int nf = 0; nf < 4; ++nf)
      bF[nf] = *reinterpret_cast<const short8*>(&sB[(wc * 64 + nf * 16 + r) * 32 + g * 8]);
#pragma unroll
    for (int mf = 0; mf < 4; ++mf)
#pragma unroll
      for (int nf = 0; nf < 4; ++nf)
        acc[mf][nf] = __builtin_amdgcn_mfma_f32_16x16x32_bf16(aF[mf], bF[nf], acc[mf][nf], 0, 0, 0);
  }

  if (MODE == 0) {
    unsigned short* outz = outb + (size_t)blockIdx.z * 8388608;
    if (blockIdx.z == 2) {
      // V^T: [b,h,d,t]
#pragma unroll
      for (int mf = 0; mf < 4; ++mf)
#pragma unroll
        for (int nf = 0; nf < 4; ++nf) {
          int m = m0 + wr * 64 + mf * 16 + g * 4;
          int n = n0 + wc * 64 + nf * 16 + r;
          int b = m >> 10, t = m & 1023, h = n >> 6, d = n & 63;
          ushort4_t pk;
          pk[0] = f2bf(acc[mf][nf][0]); pk[1] = f2bf(acc[mf][nf][1]);
          pk[2] = f2bf(acc[mf][nf][2]); pk[3] = f2bf(acc[mf][nf][3]);
          *reinterpret_cast<ushort4_t*>(
              &outz[((size_t)((b * 16 + h) * 64 + d)) * 1024 + t]) = pk;
        }
    } else {
#pragma unroll
      for (int mf = 0; mf < 4; ++mf)
#pragma unroll
        for (int nf = 0; nf < 4; ++nf)
#pragma unroll
          for (int q = 0; q < 4; ++q) {
            int m = m0 + wr * 64 + mf * 16 + g * 4 + q;
            int n = n0 + wc * 64 + nf * 16 + r;
            int b = m >> 10, t = m & 1023, h = n >> 6, d = n & 63;
            outz[(size_t)((b * 16 + h) * 1024 + t) * 64 + d] = f2bf(acc[mf][nf][q]);
          }
    }
  } else {
#pragma unroll
    for (int mf = 0; mf < 4; ++mf)
#pragma unroll
      for (int nf = 0; nf < 4; ++nf) {
        int n = n0 + wc * 64 + nf * 16 + r;
        float bv = bias[n];
#pragma unroll
        for (int q = 0; q < 4; ++q) {
          int m = m0 + wr * 64 + mf * 16 + g * 4 + q;
          outf[(size_t)m * 1024 + n] = acc[mf][nf][q] + bv;
        }
      }
  }
}

// ---------------- flash attention v3 ----------------
// S^T = Q.K^T (softmax axis j = row dim; lane owns column i), Y^T = V^T.P^T.
// Q-tile and V^T-tile staged in LDS (double-buffered, XOR-swizzled via
// pre-swizzled global source), one barrier/iter.  Block z computes the
// causal-balanced i-tile pair {z, 15-z}: 17 tile-computations per block.
__device__ __forceinline__ void softmax_pv_tile(
    floatx4 (&sT)[4], const unsigned short* __restrict__ Vb,
    floatx4 (&accYT)[4], float& m_run, float& l_run,
    int g, int r, int j0, int i_lane, bool diag) {
  // scale + causal mask
#pragma unroll
  for (int jf = 0; jf < 4; ++jf)
#pragma unroll
    for (int q = 0; q < 4; ++q) {
      float v = sT[jf][q] * 0.125f;
      if (diag && (j0 + jf * 16 + g * 4 + q > i_lane)) v = -1e30f;
      sT[jf][q] = v;
    }
  // online softmax over j (this lane's column i); reduce across g-groups
  float mx = sT[0][0];
#pragma unroll
  for (int jf = 0; jf < 4; ++jf)
#pragma unroll
    for (int q = 0; q < 4; ++q) mx = fmaxf(mx, sT[jf][q]);
  mx = fmaxf(mx, __shfl_xor(mx, 16));
  mx = fmaxf(mx, __shfl_xor(mx, 32));
  float mnew = fmaxf(m_run, mx);
  float corr = exp2f((m_run - mnew) * LOG2E);
  m_run = mnew;
  float ssum = 0.0f;
#pragma unroll
  for (int jf = 0; jf < 4; ++jf)
#pragma unroll
    for (int q = 0; q < 4; ++q) {
      float p = exp2f((sT[jf][q] - mnew) * LOG2E);
      sT[jf][q] = p;
      ssum += p;
    }
  ssum += __shfl_xor(ssum, 16);
  ssum += __shfl_xor(ssum, 32);
  l_run = l_run * corr + ssum;
#pragma unroll
  for (int df = 0; df < 4; ++df) accYT[df] *= corr;
  // P^T (C-layout) -> B-frag via packed bf16 + shuffles (verified r1-r3)
  unsigned int pk[4][2];
#pragma unroll
  for (int jf = 0; jf < 4; ++jf) {
    pk[jf][0] = pack2bf(sT[jf][0], sT[jf][1]);
    pk[jf][1] = pack2bf(sT[jf][2], sT[jf][3]);
  }
  short8 bP[2];
#pragma unroll
  for (int s = 0; s < 2; ++s) {
    uintx4 wd;
#pragma unroll
    for (int w_ = 0; w_ < 4; ++w_) {
      int src = (((g & 1) * 2 + (w_ >> 1)) << 4) + r;
      unsigned int t0 = (unsigned int)__shfl((int)pk[2 * s][w_ & 1], src);
      unsigned int t1 = (unsigned int)__shfl((int)pk[2 * s + 1][w_ & 1], src);
      wd[w_] = (g & 2) ? t1 : t0;
    }
    bP[s] = __builtin_bit_cast(short8, wd);
  }
  // Y^T += V^T . P^T ; V^T frags from swizzled LDS
  __builtin_amdgcn_s_setprio(1);
#pragma unroll
  for (int df = 0; df < 4; ++df) {
#pragma unroll
    for (int s = 0; s < 2; ++s) {
      short8 av = *reinterpret_cast<const short8*>(
          &Vb[(df * 16 + r) * 64 + ((s * 32 + g * 8) ^ ((r & 7) * 8))]);
      accYT[df] = __builtin_amdgcn_mfma_f32_16x16x32_bf16(av, bP[s], accYT[df], 0, 0, 0);
    }
  }
  __builtin_amdgcn_s_setprio(0);
}

__global__ __launch_bounds__(256, 4) void attn_kernel(
    const unsigned short* __restrict__ kqv, unsigned short* __restrict__ y) {
  const int tid = threadIdx.x;
  const int lane = tid & 63;
  const int w = tid >> 6;
  const int g = lane >> 4, r = lane & 15;
  const int bh = blockIdx.y;
  const int z = blockIdx.x;          // tile pair {z, 15-z}
  const int itA = z, itB = 15 - z;
  const int iwA = itA * 64 + w * 16; // wave's 16 i-rows, tile A
  const int iwB = itB * 64 + w * 16;

  const unsigned short* Kh = kqv + (size_t)bh * 65536;
  const unsigned short* Qh = kqv + 8388608u + (size_t)bh * 65536;
  const unsigned short* Vt = kqv + 16777216u + (size_t)bh * 65536;  // [d][t]

  __shared__ unsigned short Qs[2][64 * 64];
  __shared__ unsigned short Vs[2][64 * 64];

  // K B-frags (col=i, k=d), loaded once per tile
  short8 bKA[2], bKB[2];
#pragma unroll
  for (int s = 0; s < 2; ++s) {
    bKA[s] = *reinterpret_cast<const short8*>(&Kh[(size_t)(iwA + r) * 64 + s * 32 + g * 8]);
    bKB[s] = *reinterpret_cast<const short8*>(&Kh[(size_t)(iwB + r) * 64 + s * 32 + g * 8]);
  }

  floatx4 accA[4], accB[4];
#pragma unroll
  for (int df = 0; df < 4; ++df) { accA[df] = (floatx4)0.0f; accB[df] = (floatx4)0.0f; }
  float mA = -1e30f, lA = 0.0f, mB = -1e30f, lB = 0.0f;

  // stage tile jt into buffer bsel: Q rows + V^T rows, source pre-swizzled
  auto stage = [&](int bsel, int jts) {
    const int j0s = jts * 64;
    const int c = lane & 7;
#pragma unroll
    for (int u = 0; u < 2; ++u) {
      const int R = w * 16 + u * 8 + (lane >> 3);
      const int cc = c ^ (R & 7);
      gload_lds16(&Qh[(size_t)(j0s + R) * 64 + cc * 8], &Qs[bsel][(w * 16 + u * 8) * 64]);
      gload_lds16(&Vt[(size_t)R * 1024 + j0s + cc * 8], &Vs[bsel][(w * 16 + u * 8) * 64]);
    }
  };

  int buf = 0;
  stage(0, 0);
  __syncthreads();

  for (int jt = 0; jt <= itB; ++jt) {
    const int j0 = jt * 64;
    if (jt < itB) stage(buf ^ 1, jt + 1);

    const unsigned short* Qb = &Qs[buf][0];
    const unsigned short* Vb = &Vs[buf][0];

    // ---- tile B: S^T = Q.K_B^T
    floatx4 sT[4];
    __builtin_amdgcn_s_setprio(1);
#pragma unroll
    for (int jf = 0; jf < 4; ++jf) {
      sT[jf] = (floatx4)0.0f;
#pragma unroll
      for (int s = 0; s < 2; ++s) {
        short8 aq = *reinterpret_cast<const short8*>(
            &Qb[(jf * 16 + r) * 64 + ((s * 32 + g * 8) ^ ((r & 7) * 8))]);
        sT[jf] = __builtin_amdgcn_mfma_f32_16x16x32_bf16(aq, bKB[s], sT[jf], 0, 0, 0);
      }
    }
    __builtin_amdgcn_s_setprio(0);
    softmax_pv_tile(sT, Vb, accB, mB, lB, g, r, j0, iwB + r, jt == itB);

    // ---- tile A (active while jt <= itA)
    if (jt <= itA) {
      floatx4 sA2[4];
      __builtin_amdgcn_s_setprio(1);
#pragma unroll
      for (int jf = 0; jf < 4; ++jf) {
        sA2[jf] = (floatx4)0.0f;
#pragma unroll
        for (int s = 0; s < 2; ++s) {
          short8 aq = *reinterpret_cast<const short8*>(
              &Qb[(jf * 16 + r) * 64 + ((s * 32 + g * 8) ^ ((r & 7) * 8))]);
          sA2[jf] = __builtin_amdgcn_mfma_f32_16x16x32_bf16(aq, bKA[s], sA2[jf], 0, 0, 0);
        }
      }
      __builtin_amdgcn_s_setprio(0);
      softmax_pv_tile(sA2, Vb, accA, mA, lA, g, r, j0, iwA + r, jt == itA);
    }

    __syncthreads();   // all reads of buf done; prefetch into buf^1 landed
    buf ^= 1;
  }

  // ---- epilogue: y[b, t=i, h*64+d] = Y^T[d][i] / l
  const int b = bh >> 4, h = bh & 15;
#pragma unroll
  for (int tile = 0; tile < 2; ++tile) {
    const floatx4* acc = tile ? accB : accA;
    const float inv = 1.0f / (tile ? lB : lA);
    const int t = (tile ? iwB : iwA) + r;
    unsigned short* row = y + (size_t)(b * 1024 + t) * 1024 + h * 64;
#pragma unroll
    for (int df = 0; df < 4; ++df) {
      ushort4_t pkv;
      pkv[0] = f2bf(acc[df][0] * inv);
      pkv[1] = f2bf(acc[df][1] * inv);
      pkv[2] = f2bf(acc[df][2] * inv);
      pkv[3] = f2bf(acc[df][3] * inv);
      *reinterpret_cast<ushort4_t*>(&row[df * 16 + g * 4]) = pkv;
    }
  }
}

extern "C" void kernel_launch(void* const* d_in, const int* in_sizes, int n_in,
                              void* d_out, int out_size, void* d_ws, size_t ws_size,
                              hipStream_t stream) {
  const float* x  = (const float*)d_in[0];
  const float* Wk = (const float*)d_in[1];
  const float* Wq = (const float*)d_in[2];
  const float* Wv = (const float*)d_in[3];
  const float* Wp = (const float*)d_in[4];
  const float* bp = (const float*)d_in[5];
  float* out = (float*)d_out;

  char* ws = (char*)d_ws;
  unsigned short* xb  = (unsigned short*)ws;                  // 8M elems (reused as y)
  unsigned short* wb  = (unsigned short*)(ws + (16u << 20));  // 4 x 1M elems
  unsigned short* kqv = (unsigned short*)(ws + (24u << 20));  // K,Q [B,H,T,D]; V^T [B,H,D,T]

  cast_bf16_kernel<<<2048, 256, 0, stream>>>(x, xb, 1048576);
  cast_bf16_kernel<<<512, 256, 0, stream>>>(Wk, wb + 0 * 1048576, 131072);
  cast_bf16_kernel<<<512, 256, 0, stream>>>(Wq, wb + 1 * 1048576, 131072);
  cast_bf16_kernel<<<512, 256, 0, stream>>>(Wv, wb + 2 * 1048576, 131072);
  cast_bf16_kernel<<<512, 256, 0, stream>>>(Wp, wb + 3 * 1048576, 131072);

  dim3 gqkv(8, 64, 3);  // (N/128, M/128, 3 weights)
  gemm_kernel<0><<<gqkv, 256, 0, stream>>>(xb, wb, kqv, nullptr, nullptr);

  attn_kernel<<<dim3(8, 128), 256, 0, stream>>>(kqv, xb /* y_bf16 */);

  gemm_kernel<1><<<dim3(8, 64, 1), 256, 0, stream>>>(xb, wb + 3 * 1048576, nullptr, out, bp);
}

// Round 7
// 246.005 us; speedup vs baseline: 1.8076x; 1.1287x over previous
//
#include <hip/hip_runtime.h>
#include <hip/hip_bf16.h>

// Causal self-attention, B=8 T=1024 C=1024 H=16 D=64, fp32 in/out.
// Pipeline: cast->bf16 (1 kernel) | merged QKV gemm N=3072 (single-barrier
// dbuf BK=64, T2 swizzle, XCD swizzle; V stored transposed) | flash attn
// (unchanged from r6) | proj gemm (same new structure).
// ws: [0,16M) x_bf16 (reused as y_bf16), [16M,24M) weights bf16,
// [24M,72M) K [B,H,T,D] / Q [B,H,T,D] / V^T [B,H,D,T]. Requires ws >= 72MB.

typedef __attribute__((ext_vector_type(8))) short short8;
typedef __attribute__((ext_vector_type(8))) unsigned short ushort8;
typedef __attribute__((ext_vector_type(4))) unsigned short ushort4_t;
typedef __attribute__((ext_vector_type(4))) unsigned int uintx4;
typedef __attribute__((ext_vector_type(4))) float floatx4;

#define LOG2E 1.44269504088896f

__device__ __forceinline__ unsigned short f2bf(float f) {
  unsigned int u = __float_as_uint(f);
  u += 0x7FFFu + ((u >> 16) & 1u);   // RNE
  return (unsigned short)(u >> 16);
}

__device__ __forceinline__ unsigned int pack2bf(float lo, float hi) {
  return (unsigned int)f2bf(lo) | ((unsigned int)f2bf(hi) << 16);
}

__device__ __forceinline__ void gload_lds16(const void* g, void* l) {
  __builtin_amdgcn_global_load_lds(
      (const __attribute__((address_space(1))) unsigned int*)g,
      (__attribute__((address_space(3))) unsigned int*)l, 16, 0, 0);
}

// ---------------- fused cast fp32 -> bf16 (x + 4 weights) ----------------
__global__ __launch_bounds__(256) void cast_all_kernel(
    const float* __restrict__ x, const float* __restrict__ Wk,
    const float* __restrict__ Wq, const float* __restrict__ Wv,
    const float* __restrict__ Wp, unsigned short* __restrict__ xb,
    unsigned short* __restrict__ wb) {
  int idx = blockIdx.x * 256 + threadIdx.x;
  for (int i = idx; i < 1572864; i += 2048 * 256) {
    const float* src;
    unsigned short* dst;
    if (i < 1048576) {
      src = x + (size_t)i * 8;
      dst = xb + (size_t)i * 8;
    } else {
      int j = i - 1048576;
      int sel = j >> 17;
      int o = (j & 131071) * 8;
      const float* wsrc = sel == 0 ? Wk : sel == 1 ? Wq : sel == 2 ? Wv : Wp;
      src = wsrc + o;
      dst = wb + (size_t)sel * 1048576 + o;
    }
    const float4* p = reinterpret_cast<const float4*>(src);
    float4 a = p[0], b = p[1];
    ushort8 r;
    r[0] = f2bf(a.x); r[1] = f2bf(a.y); r[2] = f2bf(a.z); r[3] = f2bf(a.w);
    r[4] = f2bf(b.x); r[5] = f2bf(b.y); r[6] = f2bf(b.z); r[7] = f2bf(b.w);
    *reinterpret_cast<ushort8*>(dst) = r;
  }
}

// ------- bf16 GEMM v2: C[m,n] = sum_k A[m,k]*B[n,k], K=1024, M=8192 -------
// 128x128 tile, BK=64, single-barrier double-buffered LDS (T3-minimum),
// T2 XOR-swizzle (pre-swizzled global source + swizzled ds_read),
// bijective chunked XCD swizzle, n-fastest block order (A-panel L2 reuse).
// MODE 0: NB=24 (N=3072, merged Wk/Wq/Wv). n<2048 -> K/Q bf16 [B,H,T,D];
//         n>=2048 (V) -> bf16 TRANSPOSED [B,H,D,T].
// MODE 1: NB=8 (N=1024, Wp) -> fp32 [8192x1024] + bias.
template <int MODE, int NB>
__global__ __launch_bounds__(256) void gemm2_kernel(
    const unsigned short* __restrict__ A, const unsigned short* __restrict__ Bb,
    unsigned short* __restrict__ outb, float* __restrict__ outf,
    const float* __restrict__ bias) {
  const int tid = threadIdx.x;
  const int lane = tid & 63;
  const int w = tid >> 6;
  const int wr = w >> 1, wc = w & 1;
  const int g = lane >> 4, r = lane & 15;

  constexpr int NWG = NB * 64;
  constexpr int CPX = NWG / 8;  // NWG % 8 == 0 for NB=24,8 -> bijective
  const int bid = blockIdx.x;
  const int wgid = (bid & 7) * CPX + (bid >> 3);
  const int mb = wgid / NB, nb = wgid % NB;  // n fastest: A-panel reuse in L2
  const int m0 = mb * 128, n0 = nb * 128;

  __shared__ unsigned short sA[2][128 * 64];
  __shared__ unsigned short sB[2][128 * 64];

  floatx4 acc[4][4];
#pragma unroll
  for (int i = 0; i < 4; ++i)
#pragma unroll
    for (int j = 0; j < 4; ++j) acc[i][j] = (floatx4)0.0f;

  const int su = lane >> 3;        // row-within-8 for staging
  const int sc = (lane & 7) ^ su;  // pre-swizzled source chunk (involution)

  // stage K-tile kt (128 rows x 64 cols, A and B) into buffer bsel.
  // LDS dest is wave-uniform + lane*16B (linear); source chunk pre-swizzled
  // so that LDS[row][c] = global[row][c ^ (row&7)]  (16B chunk units).
  auto stage = [&](int bsel, int kt) {
#pragma unroll
    for (int u = 0; u < 4; ++u) {
      const int row = u * 32 + w * 8 + su;  // row&7 == su
      gload_lds16(&A[(size_t)(m0 + row) * 1024 + kt * 64 + sc * 8],
                  &sA[bsel][(u * 32 + w * 8) * 64]);
      gload_lds16(&Bb[(size_t)(n0 + row) * 1024 + kt * 64 + sc * 8],
                  &sB[bsel][(u * 32 + w * 8) * 64]);
    }
  };

  int buf = 0;
  stage(0, 0);
  __syncthreads();  // prologue drain (compiler emits vmcnt(0) before barrier)

  for (int kt = 0; kt < 16; ++kt) {
    if (kt < 15) stage(buf ^ 1, kt + 1);  // issue BEFORE compute: overlaps MFMA
#pragma unroll
    for (int kk = 0; kk < 2; ++kk) {
      short8 aF[4], bF[4];
#pragma unroll
      for (int mf = 0; mf < 4; ++mf) {
        const int row = wr * 64 + mf * 16 + r;  // row&7 == r&7
        aF[mf] = *reinterpret_cast<const short8*>(
            &sA[buf][row * 64 + (((kk * 4 + g) ^ (r & 7)) * 8)]);
      }
#pragma unroll
      for (int nf = 0; nf < 4; ++nf) {
        const int row = wc * 64 + nf * 16 + r;
        bF[nf] = *reinterpret_cast<const short8*>(
            &sB[buf][row * 64 + (((kk * 4 + g) ^ (r & 7)) * 8)]);
      }
#pragma unroll
      for (int mf = 0; mf < 4; ++mf)
#pragma unroll
        for (int nf = 0; nf < 4; ++nf)
          acc[mf][nf] = __builtin_amdgcn_mfma_f32_16x16x32_bf16(
              aF[mf], bF[nf], acc[mf][nf], 0, 0, 0);
    }
    __syncthreads();  // readers of buf done; stage->buf^1 drained
    buf ^= 1;
  }

  if (MODE == 0) {
    const int zB = n0 >> 10;  // block-uniform (128 | 1024)
    unsigned short* outz = outb + (size_t)zB * 8388608;
    if (zB == 2) {
      // V^T: [b,h,d,t], pack 4 consecutive t (q=0..3)
#pragma unroll
      for (int mf = 0; mf < 4; ++mf)
#pragma unroll
        for (int nf = 0; nf < 4; ++nf) {
          int m = m0 + wr * 64 + mf * 16 + g * 4;
          int nn = n0 + wc * 64 + nf * 16 + r;
          int b = m >> 10, t = m & 1023, h = (nn & 1023) >> 6, d = nn & 63;
          ushort4_t pk;
          pk[0] = f2bf(acc[mf][nf][0]); pk[1] = f2bf(acc[mf][nf][1]);
          pk[2] = f2bf(acc[mf][nf][2]); pk[3] = f2bf(acc[mf][nf][3]);
          *reinterpret_cast<ushort4_t*>(
              &outz[((size_t)((b * 16 + h) * 64 + d)) * 1024 + t]) = pk;
        }
    } else {
#pragma unroll
      for (int mf = 0; mf < 4; ++mf)
#pragma unroll
        for (int nf = 0; nf < 4; ++nf)
#pragma unroll
          for (int q = 0; q < 4; ++q) {
            int m = m0 + wr * 64 + mf * 16 + g * 4 + q;
            int nn = n0 + wc * 64 + nf * 16 + r;
            int b = m >> 10, t = m & 1023, h = (nn & 1023) >> 6, d = nn & 63;
            outz[(size_t)((b * 16 + h) * 1024 + t) * 64 + d] = f2bf(acc[mf][nf][q]);
          }
    }
  } else {
#pragma unroll
    for (int mf = 0; mf < 4; ++mf)
#pragma unroll
      for (int nf = 0; nf < 4; ++nf) {
        int nn = n0 + wc * 64 + nf * 16 + r;
        float bv = bias[nn];
#pragma unroll
        for (int q = 0; q < 4; ++q) {
          int m = m0 + wr * 64 + mf * 16 + g * 4 + q;
          outf[(size_t)m * 1024 + nn] = acc[mf][nf][q] + bv;
        }
      }
  }
}

// ---------------- flash attention (unchanged from round 6, PASSED) --------
// S^T = Q.K^T (softmax axis j = row dim; lane owns column i), Y^T = V^T.P^T.
// Q-tile and V^T-tile staged in LDS (double-buffered, XOR-swizzled via
// pre-swizzled global source), one barrier/iter.  Block z computes the
// causal-balanced i-tile pair {z, 15-z}: 17 tile-computations per block.
__device__ __forceinline__ void softmax_pv_tile(
    floatx4 (&sT)[4], const unsigned short* __restrict__ Vb,
    floatx4 (&accYT)[4], float& m_run, float& l_run,
    int g, int r, int j0, int i_lane, bool diag) {
  // scale + causal mask
#pragma unroll
  for (int jf = 0; jf < 4; ++jf)
#pragma unroll
    for (int q = 0; q < 4; ++q) {
      float v = sT[jf][q] * 0.125f;
      if (diag && (j0 + jf * 16 + g * 4 + q > i_lane)) v = -1e30f;
      sT[jf][q] = v;
    }
  // online softmax over j (this lane's column i); reduce across g-groups
  float mx = sT[0][0];
#pragma unroll
  for (int jf = 0; jf < 4; ++jf)
#pragma unroll
    for (int q = 0; q < 4; ++q) mx = fmaxf(mx, sT[jf][q]);
  mx = fmaxf(mx, __shfl_xor(mx, 16));
  mx = fmaxf(mx, __shfl_xor(mx, 32));
  float mnew = fmaxf(m_run, mx);
  float corr = exp2f((m_run - mnew) * LOG2E);
  m_run = mnew;
  float ssum = 0.0f;
#pragma unroll
  for (int jf = 0; jf < 4; ++jf)
#pragma unroll
    for (int q = 0; q < 4; ++q) {
      float p = exp2f((sT[jf][q] - mnew) * LOG2E);
      sT[jf][q] = p;
      ssum += p;
    }
  ssum += __shfl_xor(ssum, 16);
  ssum += __shfl_xor(ssum, 32);
  l_run = l_run * corr + ssum;
#pragma unroll
  for (int df = 0; df < 4; ++df) accYT[df] *= corr;
  // P^T (C-layout) -> B-frag via packed bf16 + shuffles (verified r1-r6)
  unsigned int pk[4][2];
#pragma unroll
  for (int jf = 0; jf < 4; ++jf) {
    pk[jf][0] = pack2bf(sT[jf][0], sT[jf][1]);
    pk[jf][1] = pack2bf(sT[jf][2], sT[jf][3]);
  }
  short8 bP[2];
#pragma unroll
  for (int s = 0; s < 2; ++s) {
    uintx4 wd;
#pragma unroll
    for (int w_ = 0; w_ < 4; ++w_) {
      int src = (((g & 1) * 2 + (w_ >> 1)) << 4) + r;
      unsigned int t0 = (unsigned int)__shfl((int)pk[2 * s][w_ & 1], src);
      unsigned int t1 = (unsigned int)__shfl((int)pk[2 * s + 1][w_ & 1], src);
      wd[w_] = (g & 2) ? t1 : t0;
    }
    bP[s] = __builtin_bit_cast(short8, wd);
  }
  // Y^T += V^T . P^T ; V^T frags from swizzled LDS
  __builtin_amdgcn_s_setprio(1);
#pragma unroll
  for (int df = 0; df < 4; ++df) {
#pragma unroll
    for (int s = 0; s < 2; ++s) {
      short8 av = *reinterpret_cast<const short8*>(
          &Vb[(df * 16 + r) * 64 + ((s * 32 + g * 8) ^ ((r & 7) * 8))]);
      accYT[df] = __builtin_amdgcn_mfma_f32_16x16x32_bf16(av, bP[s], accYT[df], 0, 0, 0);
    }
  }
  __builtin_amdgcn_s_setprio(0);
}

__global__ __launch_bounds__(256, 4) void attn_kernel(
    const unsigned short* __restrict__ kqv, unsigned short* __restrict__ y) {
  const int tid = threadIdx.x;
  const int lane = tid & 63;
  const int w = tid >> 6;
  const int g = lane >> 4, r = lane & 15;
  const int bh = blockIdx.y;
  const int z = blockIdx.x;          // tile pair {z, 15-z}
  const int itA = z, itB = 15 - z;
  const int iwA = itA * 64 + w * 16; // wave's 16 i-rows, tile A
  const int iwB = itB * 64 + w * 16;

  const unsigned short* Kh = kqv + (size_t)bh * 65536;
  const unsigned short* Qh = kqv + 8388608u + (size_t)bh * 65536;
  const unsigned short* Vt = kqv + 16777216u + (size_t)bh * 65536;  // [d][t]

  __shared__ unsigned short Qs[2][64 * 64];
  __shared__ unsigned short Vs[2][64 * 64];

  // K B-frags (col=i, k=d), loaded once per tile
  short8 bKA[2], bKB[2];
#pragma unroll
  for (int s = 0; s < 2; ++s) {
    bKA[s] = *reinterpret_cast<const short8*>(&Kh[(size_t)(iwA + r) * 64 + s * 32 + g * 8]);
    bKB[s] = *reinterpret_cast<const short8*>(&Kh[(size_t)(iwB + r) * 64 + s * 32 + g * 8]);
  }

  floatx4 accA[4], accB[4];
#pragma unroll
  for (int df = 0; df < 4; ++df) { accA[df] = (floatx4)0.0f; accB[df] = (floatx4)0.0f; }
  float mA = -1e30f, lA = 0.0f, mB = -1e30f, lB = 0.0f;

  // stage tile jt into buffer bsel: Q rows + V^T rows, source pre-swizzled
  auto stage = [&](int bsel, int jts) {
    const int j0s = jts * 64;
    const int c = lane & 7;
#pragma unroll
    for (int u = 0; u < 2; ++u) {
      const int R = w * 16 + u * 8 + (lane >> 3);
      const int cc = c ^ (R & 7);
      gload_lds16(&Qh[(size_t)(j0s + R) * 64 + cc * 8], &Qs[bsel][(w * 16 + u * 8) * 64]);
      gload_lds16(&Vt[(size_t)R * 1024 + j0s + cc * 8], &Vs[bsel][(w * 16 + u * 8) * 64]);
    }
  };

  int buf = 0;
  stage(0, 0);
  __syncthreads();

  for (int jt = 0; jt <= itB; ++jt) {
    const int j0 = jt * 64;
    if (jt < itB) stage(buf ^ 1, jt + 1);

    const unsigned short* Qb = &Qs[buf][0];
    const unsigned short* Vb = &Vs[buf][0];

    // ---- tile B: S^T = Q.K_B^T
    floatx4 sT[4];
    __builtin_amdgcn_s_setprio(1);
#pragma unroll
    for (int jf = 0; jf < 4; ++jf) {
      sT[jf] = (floatx4)0.0f;
#pragma unroll
      for (int s = 0; s < 2; ++s) {
        short8 aq = *reinterpret_cast<const short8*>(
            &Qb[(jf * 16 + r) * 64 + ((s * 32 + g * 8) ^ ((r & 7) * 8))]);
        sT[jf] = __builtin_amdgcn_mfma_f32_16x16x32_bf16(aq, bKB[s], sT[jf], 0, 0, 0);
      }
    }
    __builtin_amdgcn_s_setprio(0);
    softmax_pv_tile(sT, Vb, accB, mB, lB, g, r, j0, iwB + r, jt == itB);

    // ---- tile A (active while jt <= itA)
    if (jt <= itA) {
      floatx4 sA2[4];
      __builtin_amdgcn_s_setprio(1);
#pragma unroll
      for (int jf = 0; jf < 4; ++jf) {
        sA2[jf] = (floatx4)0.0f;
#pragma unroll
        for (int s = 0; s < 2; ++s) {
          short8 aq = *reinterpret_cast<const short8*>(
              &Qb[(jf * 16 + r) * 64 + ((s * 32 + g * 8) ^ ((r & 7) * 8))]);
          sA2[jf] = __builtin_amdgcn_mfma_f32_16x16x32_bf16(aq, bKA[s], sA2[jf], 0, 0, 0);
        }
      }
      __builtin_amdgcn_s_setprio(0);
      softmax_pv_tile(sA2, Vb, accA, mA, lA, g, r, j0, iwA + r, jt == itA);
    }

    __syncthreads();   // all reads of buf done; prefetch into buf^1 landed
    buf ^= 1;
  }

  // ---- epilogue: y[b, t=i, h*64+d] = Y^T[d][i] / l
  const int b = bh >> 4, h = bh & 15;
#pragma unroll
  for (int tile = 0; tile < 2; ++tile) {
    const floatx4* acc = tile ? accB : accA;
    const float inv = 1.0f / (tile ? lB : lA);
    const int t = (tile ? iwB : iwA) + r;
    unsigned short* row = y + (size_t)(b * 1024 + t) * 1024 + h * 64;
#pragma unroll
    for (int df = 0; df < 4; ++df) {
      ushort4_t pkv;
      pkv[0] = f2bf(acc[df][0] * inv);
      pkv[1] = f2bf(acc[df][1] * inv);
      pkv[2] = f2bf(acc[df][2] * inv);
      pkv[3] = f2bf(acc[df][3] * inv);
      *reinterpret_cast<ushort4_t*>(&row[df * 16 + g * 4]) = pkv;
    }
  }
}

extern "C" void kernel_launch(void* const* d_in, const int* in_sizes, int n_in,
                              void* d_out, int out_size, void* d_ws, size_t ws_size,
                              hipStream_t stream) {
  const float* x  = (const float*)d_in[0];
  const float* Wk = (const float*)d_in[1];
  const float* Wq = (const float*)d_in[2];
  const float* Wv = (const float*)d_in[3];
  const float* Wp = (const float*)d_in[4];
  const float* bp = (const float*)d_in[5];
  float* out = (float*)d_out;

  char* ws = (char*)d_ws;
  unsigned short* xb  = (unsigned short*)ws;                  // 8M elems (reused as y)
  unsigned short* wb  = (unsigned short*)(ws + (16u << 20));  // 4 x 1M elems: Wk,Wq,Wv,Wp
  unsigned short* kqv = (unsigned short*)(ws + (24u << 20));  // K,Q [B,H,T,D]; V^T [B,H,D,T]

  cast_all_kernel<<<2048, 256, 0, stream>>>(x, Wk, Wq, Wv, Wp, xb, wb);

  gemm2_kernel<0, 24><<<1536, 256, 0, stream>>>(xb, wb, kqv, nullptr, nullptr);

  attn_kernel<<<dim3(8, 128), 256, 0, stream>>>(kqv, xb /* y_bf16 */);

  gemm2_kernel<1, 8><<<512, 256, 0, stream>>>(xb, wb + 3 * 1048576, nullptr, out, bp);
}